// Round 3
// baseline (1114.590 us; speedup 1.0000x reference)
//
#include <hip/hip_runtime.h>
#include <math.h>

#define EPSF 1e-6f
#define BP_ITERS 7

// ---- d_out layout (float offsets) ----
#define OFF_A    0ull
#define OFF_B1   33554432ull
#define OFF_B2   33882112ull
#define OFF_B3   34209792ull
#define OFF_AF1  34537472ull
#define OFF_AF2  68091904ull
#define OFF_AF3  101646336ull
// scratch parked inside d_out (regions dead until later kernels overwrite them)
#define Y1_OFF  (OFF_AF1)                 // [B][512][64] fp32
#define X1_OFF  (OFF_AF1 + 4194304ull)    // [B][512][64] fp32
#define Y2_OFF  (OFF_AF2)                 // [B][512][32] fp32
#define X2_OFF  (OFF_AF2 + 2097152ull)    // [B][512][32] fp32
#define AT_OFF  (OFF_AF2 + 4194304ull)    // At[b][j(512)][i(256)] = A[b][256+i][j]
#define RS_OFF  (OFF_AF3)                 // [B*512] rowsum(A) fp32 (overwritten by k_aff at the end)
#define PARK1(b) (OFF_B3 + (size_t)(b)*2560ull + 2500ull)
#define PARK2(b) (OFF_B3 + (size_t)(b)*2560ull + 2525ull)

typedef __attribute__((ext_vector_type(8))) short bf16x8;
typedef __attribute__((ext_vector_type(4))) short s16x4;
typedef __attribute__((ext_vector_type(4))) float f32x4;

__device__ __forceinline__ short f2bf(float f) {
  unsigned u = __float_as_uint(f);
  unsigned r = (u + 0x7fffu + ((u >> 16) & 1u)) >> 16;
  return (short)r;
}
__device__ __forceinline__ float bf2f(short h) {
  return __uint_as_float(((unsigned)(unsigned short)h) << 16);
}

__device__ __forceinline__ void unpack15(float4 q0, float4 q1, float4 q2, float4 q3, float* o) {
  o[0]=q0.x; o[1]=q0.y; o[2]=q0.z; o[3]=q0.w;
  o[4]=q1.x; o[5]=q1.y; o[6]=q1.z; o[7]=q1.w;
  o[8]=q2.x; o[9]=q2.y; o[10]=q2.z; o[11]=q2.w;
  o[12]=q3.x; o[13]=q3.y; o[14]=q3.z;
}

// ---------------- 1. row sums of A ----------------
__global__ __launch_bounds__(256) void k_rowsum(const float* __restrict__ A, float* __restrict__ rs) {
  int wid = threadIdx.x >> 6, lane = threadIdx.x & 63;
  for (int rr = 0; rr < 2; ++rr) {
    size_t row = (size_t)blockIdx.x * 8 + wid * 2 + rr; // = b*512+n
    const float4* src = (const float4*)(A + row * 512);
    float4 v0 = src[lane * 2], v1 = src[lane * 2 + 1];
    float s = v0.x + v0.y + v0.z + v0.w + v1.x + v1.y + v1.z + v1.w;
    #pragma unroll
    for (int off = 1; off < 64; off <<= 1) s += __shfl_xor(s, off, 64);
    if (lane == 0) rs[row] = s;
  }
}

// ---------------- 2. split-bf16 MFMA GEMM: C[b](512xBN) = A[b](512xK) @ B(KxBN) ----------------
template<int BN, bool POST>
__global__ __launch_bounds__(256) void k_mgemm(const float* __restrict__ Ain, size_t astride,
                                               const float* __restrict__ Bin, size_t bstride,
                                               float* __restrict__ Cout,
                                               const float* __restrict__ rowsum,
                                               const float* __restrict__ bias, int K) {
  constexpr int BM = 128, BK = 64, LDA = BK + 8;
  constexpr int NF = BN / 16;
  __shared__ short Ahi[BM * LDA], Alo[BM * LDA];
  __shared__ short Bhi[BN * LDA], Blo[BN * LDA];
  __shared__ float rs[BM];
  __shared__ float bls[BN];
  int b = blockIdx.x >> 2, mt = blockIdx.x & 3;
  int m0 = mt * BM;
  int t = threadIdx.x;
  int w = t >> 6, l = t & 63;
  if constexpr (POST) {
    if (t < BM) rs[t] = rowsum[(size_t)b * 512 + m0 + t];
    if (t < BN) bls[t] = bias[t];
  }
  const float* Ab = Ain + (size_t)b * astride + (size_t)m0 * K;
  const float* Bb = Bin + (size_t)b * bstride;
  f32x4 acc[2][NF];
  #pragma unroll
  for (int mf = 0; mf < 2; ++mf)
    #pragma unroll
    for (int nf = 0; nf < NF; ++nf) acc[mf][nf] = (f32x4){0.f, 0.f, 0.f, 0.f};

  for (int kt = 0; kt < K; kt += BK) {
    #pragma unroll
    for (int i = 0; i < 8; ++i) {
      int f = (t + i * 256) * 4;
      int r = f >> 6, k = f & 63;
      float4 v = *(const float4*)(Ab + (size_t)r * K + kt + k);
      float xs[4] = {v.x, v.y, v.z, v.w};
      s16x4 h, lo;
      #pragma unroll
      for (int e = 0; e < 4; ++e) {
        h[e] = f2bf(xs[e]);
        lo[e] = f2bf(xs[e] - bf2f(h[e]));
      }
      *(s16x4*)&Ahi[r * LDA + k] = h;
      *(s16x4*)&Alo[r * LDA + k] = lo;
    }
    #pragma unroll
    for (int i = 0; i < BK * BN / 1024; ++i) {
      int f = (t + i * 256) * 4;
      int k = f / BN, n = f % BN;
      float4 v = *(const float4*)(Bb + (size_t)(kt + k) * BN + n);
      float xs[4] = {v.x, v.y, v.z, v.w};
      #pragma unroll
      for (int e = 0; e < 4; ++e) {
        short h = f2bf(xs[e]);
        Bhi[(n + e) * LDA + k] = h;
        Blo[(n + e) * LDA + k] = f2bf(xs[e] - bf2f(h));
      }
    }
    __syncthreads();
    #pragma unroll
    for (int kc = 0; kc < 2; ++kc) {
      int kb = kc * 32 + (l >> 4) * 8;
      bf16x8 ah[2], al[2];
      #pragma unroll
      for (int mf = 0; mf < 2; ++mf) {
        int row = w * 32 + mf * 16 + (l & 15);
        ah[mf] = *(const bf16x8*)&Ahi[row * LDA + kb];
        al[mf] = *(const bf16x8*)&Alo[row * LDA + kb];
      }
      #pragma unroll
      for (int nf = 0; nf < NF; ++nf) {
        int col = nf * 16 + (l & 15);
        bf16x8 bh = *(const bf16x8*)&Bhi[col * LDA + kb];
        bf16x8 bl = *(const bf16x8*)&Blo[col * LDA + kb];
        #pragma unroll
        for (int mf = 0; mf < 2; ++mf) {
          acc[mf][nf] = __builtin_amdgcn_mfma_f32_16x16x32_bf16(ah[mf], bh, acc[mf][nf], 0, 0, 0);
          acc[mf][nf] = __builtin_amdgcn_mfma_f32_16x16x32_bf16(ah[mf], bl, acc[mf][nf], 0, 0, 0);
          acc[mf][nf] = __builtin_amdgcn_mfma_f32_16x16x32_bf16(al[mf], bh, acc[mf][nf], 0, 0, 0);
        }
      }
    }
    __syncthreads();
  }
  #pragma unroll
  for (int mf = 0; mf < 2; ++mf) {
    #pragma unroll
    for (int nf = 0; nf < NF; ++nf) {
      int col = nf * 16 + (l & 15);
      #pragma unroll
      for (int i = 0; i < 4; ++i) {
        int rloc = w * 32 + mf * 16 + (l >> 4) * 4 + i;
        float x = acc[mf][nf][i];
        if constexpr (POST) x = fmaxf(x / (rs[rloc] + EPSF) + bls[col], 0.f);
        Cout[((size_t)b * 512 + m0 + rloc) * BN + col] = x;
      }
    }
  }
}

// ---------------- 3. binary_comp_calc ----------------
template<int D>
__global__ __launch_bounds__(256) void k_bc(const float* __restrict__ X, const int* __restrict__ labels,
                                            float* __restrict__ dst, int parkoff) {
  constexpr int SL = 256 / D;
  constexpr int NPER = 512 / SL;
  __shared__ int labs[512];
  __shared__ float part[SL * 5 * D];
  __shared__ float cnt[5], nrm[5], proto[5 * D], dots[25];
  int b = blockIdx.x, t = threadIdx.x;
  labs[t] = labels[b * 512 + t];
  labs[t + 256] = labels[b * 512 + 256 + t];
  if (t < 5) { cnt[t] = 0.f; nrm[t] = 0.f; }
  __syncthreads();
  if (t < 128) {
    #pragma unroll
    for (int k = 0; k < 4; ++k) atomicAdd(&cnt[labs[t * 4 + k]], 1.f);
  }
  {
    int s = t / D, d = t % D;
    float a5[5] = {};
    for (int k = 0; k < NPER; ++k) {
      int n = s * NPER + k;
      float x = X[((size_t)b * 512 + n) * D + d];
      int lab = labs[n];
      #pragma unroll
      for (int w = 0; w < 5; ++w) a5[w] += (lab == w) ? x : 0.f;
    }
    #pragma unroll
    for (int w = 0; w < 5; ++w) part[(s * 5 + w) * D + d] = a5[w];
  }
  __syncthreads();
  for (int idx = t; idx < 5 * D; idx += 256) {
    int w = idx / D, dd = idx % D;
    float p = 0.f;
    #pragma unroll
    for (int s2 = 0; s2 < SL; ++s2) p += part[(s2 * 5 + w) * D + dd];
    p /= (cnt[w] + EPSF);
    proto[w * D + dd] = p;
    atomicAdd(&nrm[w], p * p);
  }
  __syncthreads();
  if (t < 25) {
    int w = t / 5, v = t % 5;
    float sdot = 0.f;
    for (int dd = 0; dd < D; ++dd) sdot += proto[w * D + dd] * proto[v * D + dd];
    dots[t] = sdot / ((sqrtf(nrm[w]) + EPSF) * (sqrtf(nrm[v]) + EPSF));
  }
  __syncthreads();
  if (t < 25) {
    int w = t / 5;
    float m = dots[w * 5];
    #pragma unroll
    for (int u = 1; u < 5; ++u) m = fmaxf(m, dots[w * 5 + u]);
    float ssum = 0.f;
    #pragma unroll
    for (int u = 0; u < 5; ++u) ssum += expf(dots[w * 5 + u] - m);
    dst[(size_t)b * 2560 + parkoff + t] = expf(dots[t] - m) / ssum;
  }
}

// ---------------- 4. transpose rows 256..511 of A: At[b][j][i] = A[b][256+i][j] ----------------
__global__ __launch_bounds__(256) void k_At(const float* __restrict__ A, float* __restrict__ Atr) {
  __shared__ float T[64][65];
  int bid = blockIdx.x;
  int b = bid >> 5, r = bid & 31, jt = r >> 2, it = r & 3;
  int j0 = jt * 64, i0 = it * 64;
  int t = threadIdx.x;
  #pragma unroll
  for (int c = 0; c < 4; ++c) {
    int flat = (t + c * 256) * 4;
    int ii = flat >> 6, jj = flat & 63;
    float4 v = *(const float4*)(A + ((size_t)b * 512 + 256 + i0 + ii) * 512 + j0 + jj);
    T[ii][jj] = v.x; T[ii][jj + 1] = v.y; T[ii][jj + 2] = v.z; T[ii][jj + 3] = v.w;
  }
  __syncthreads();
  #pragma unroll
  for (int c = 0; c < 4; ++c) {
    int flat = (t + c * 256) * 4;
    int jj = flat >> 6, ii = flat & 63;
    float4 v = make_float4(T[ii][jj], T[ii + 1][jj], T[ii + 2][jj], T[ii + 3][jj]);
    *(float4*)(Atr + ((size_t)b * 512 + j0 + jj) * 256 + i0 + ii) = v;
  }
}

// ---------------- 5. fused 3-round BP: 1024 threads, A register-resident ----------------
__global__ __launch_bounds__(1024) void k_bp(const float* __restrict__ Atr,
                                             const float* __restrict__ unary,
                                             const float* __restrict__ binc,
                                             const int* __restrict__ labels,
                                             float* __restrict__ out) {
  __shared__ float cbuf[256 * 20];     // c[j][k], k=r*5+v (15 used); support-c in prologue, free-c in iters
  __shared__ float b3s[3 * 256 * 5];   // free-node beliefs
  __shared__ float msg[256 * 17];      // ds_add combine target, stride 17 (odd -> conflict-free)
  __shared__ float u_ls[256 * 5];      // free-node unary
  __shared__ float binl[3 * 5 * 8];
  __shared__ int labs[512];
  int b = blockIdx.x, t = threadIdx.x;
  int w = t >> 6, l = t & 63;          // 16 waves; wave w owns j-chunk [16w, 16w+16)
  if (t < 512) labs[t] = labels[b * 512 + t];
  if (t < 75) {
    int r = t / 25, wv = t % 25, ww = wv / 5, v = wv % 5;
    float val;
    if (r == 0)      val = binc[b * 25 + wv];
    else if (r == 1) val = out[PARK1(b) + wv];
    else             val = out[PARK2(b) + wv];
    binl[r * 40 + ww * 8 + v] = val;
  }
  __syncthreads();
  // P1 (t<256): unary -> LDS, b0 = softmax(u), support c rows into cbuf
  if (t < 256) {
    float u[5];
    size_t ub = ((size_t)b * 512 + 256 + t) * 5;
    #pragma unroll
    for (int v = 0; v < 5; ++v) { u[v] = unary[ub + v]; u_ls[t * 5 + v] = u[v]; }
    float m = u[0];
    #pragma unroll
    for (int v = 1; v < 5; ++v) m = fmaxf(m, u[v]);
    float e[5], ssum = 0.f;
    #pragma unroll
    for (int v = 0; v < 5; ++v) { e[v] = expf(u[v] - m); ssum += e[v]; }
    float inv = 1.f / ssum;
    #pragma unroll
    for (int r = 0; r < 3; ++r)
      #pragma unroll
      for (int ww = 0; ww < 5; ++ww) b3s[r * 1280 + t * 5 + ww] = e[ww] * inv;
    int lab = labs[t];
    #pragma unroll
    for (int r = 0; r < 3; ++r)
      #pragma unroll
      for (int v = 0; v < 5; ++v) cbuf[t * 20 + r * 5 + v] = binl[r * 40 + lab * 8 + v];
    cbuf[t * 20 + 15] = 0.f;
  }
  __syncthreads();
  // P2: support partial asup (held in regs) + load free-block A into regs (held across all iters)
  float asup[4][15] = {};
  float af[16][4];
  #pragma unroll
  for (int jj = 0; jj < 16; ++jj) {
    int j = w * 16 + jj;
    const float4* cq = (const float4*)&cbuf[j * 20];
    float ck[15]; unpack15(cq[0], cq[1], cq[2], cq[3], ck);
    size_t sbase = ((size_t)b * 512 + j) * 256 + l;
    float a0 = Atr[sbase], a1 = Atr[sbase + 64], a2 = Atr[sbase + 128], a3 = Atr[sbase + 192];
    #pragma unroll
    for (int k = 0; k < 15; ++k) {
      asup[0][k] += a0 * ck[k]; asup[1][k] += a1 * ck[k];
      asup[2][k] += a2 * ck[k]; asup[3][k] += a3 * ck[k];
    }
    size_t fbase = ((size_t)b * 512 + 256 + j) * 256 + l;
    af[jj][0] = Atr[fbase];       af[jj][1] = Atr[fbase + 64];
    af[jj][2] = Atr[fbase + 128]; af[jj][3] = Atr[fbase + 192];
  }
  __syncthreads();
  for (int it = 0; it < BP_ITERS; ++it) {
    // A-phase (t<256): c[t] = b[t] @ binary ; zero msg (all threads)
    if (t < 256) {
      float bb[15];
      #pragma unroll
      for (int r = 0; r < 3; ++r)
        #pragma unroll
        for (int ww = 0; ww < 5; ++ww) bb[r * 5 + ww] = b3s[r * 1280 + t * 5 + ww];
      float c15[15];
      #pragma unroll
      for (int r = 0; r < 3; ++r)
        #pragma unroll
        for (int v = 0; v < 5; ++v) {
          float s = 0.f;
          #pragma unroll
          for (int ww = 0; ww < 5; ++ww) s += bb[r * 5 + ww] * binl[r * 40 + ww * 8 + v];
          c15[r * 5 + v] = s;
        }
      float4* cq = (float4*)&cbuf[t * 20];
      cq[0] = make_float4(c15[0], c15[1], c15[2], c15[3]);
      cq[1] = make_float4(c15[4], c15[5], c15[6], c15[7]);
      cq[2] = make_float4(c15[8], c15[9], c15[10], c15[11]);
      cq[3] = make_float4(c15[12], c15[13], c15[14], 0.f);
    }
    #pragma unroll
    for (int idx = t; idx < 256 * 17; idx += 1024) msg[idx] = 0.f;
    __syncthreads();
    // B-phase: all 16 waves, register A, j-chunk of 16
    {
      float acc[4][15];
      #pragma unroll
      for (int dr = 0; dr < 4; ++dr)
        #pragma unroll
        for (int k = 0; k < 15; ++k) acc[dr][k] = asup[dr][k];
      #pragma unroll
      for (int jj = 0; jj < 16; ++jj) {
        int j = w * 16 + jj;
        const float4* cq = (const float4*)&cbuf[j * 20];
        float ck[15]; unpack15(cq[0], cq[1], cq[2], cq[3], ck);
        #pragma unroll
        for (int k = 0; k < 15; ++k) {
          acc[0][k] += af[jj][0] * ck[k]; acc[1][k] += af[jj][1] * ck[k];
          acc[2][k] += af[jj][2] * ck[k]; acc[3][k] += af[jj][3] * ck[k];
        }
      }
      #pragma unroll
      for (int dr = 0; dr < 4; ++dr)
        #pragma unroll
        for (int k = 0; k < 15; ++k) atomicAdd(&msg[(l + 64 * dr) * 17 + k], acc[dr][k]);
    }
    __syncthreads();
    // C-phase (t<768): (r,row) = (t>>8, t&255): b = softmax(u + msg)
    if (t < 768) {
      int r = t >> 8, row = t & 255;
      float lg[5];
      #pragma unroll
      for (int v = 0; v < 5; ++v) lg[v] = u_ls[row * 5 + v] + msg[row * 17 + r * 5 + v];
      float m = lg[0];
      #pragma unroll
      for (int v = 1; v < 5; ++v) m = fmaxf(m, lg[v]);
      float e[5], ssum = 0.f;
      #pragma unroll
      for (int v = 0; v < 5; ++v) { e[v] = expf(lg[v] - m); ssum += e[v]; }
      float inv = 1.f / ssum;
      #pragma unroll
      for (int ww = 0; ww < 5; ++ww) b3s[r * 1280 + row * 5 + ww] = e[ww] * inv;
    }
    __syncthreads();
  }
  // P4 (t<512): write clamped beliefs to the three output sections
  if (t < 512) {
    int n = t;
    float bel[15];
    if (n < 256) {
      int lab = labs[n];
      #pragma unroll
      for (int r = 0; r < 3; ++r)
        #pragma unroll
        for (int v = 0; v < 5; ++v) bel[r * 5 + v] = (v == lab) ? 1.f : 0.f;
    } else {
      int fr = n - 256;
      #pragma unroll
      for (int r = 0; r < 3; ++r)
        #pragma unroll
        for (int ww = 0; ww < 5; ++ww) bel[r * 5 + ww] = b3s[r * 1280 + fr * 5 + ww];
    }
    size_t rowb = (size_t)b * 512 + n;
    #pragma unroll
    for (int v = 0; v < 5; ++v) {
      out[OFF_B1 + rowb * 5 + v] = bel[v];
      out[OFF_B2 + rowb * 5 + v] = bel[5 + v];
      out[OFF_B3 + rowb * 5 + v] = bel[10 + v];
    }
  }
}

// ---------------- 6. fused affinity pass: A-copy + aff1 + aff2 + aff3 in one sweep ----------------
__global__ __launch_bounds__(256) void k_aff(const float* __restrict__ A, float* __restrict__ out) {
  __shared__ float belT[16][520];   // [k][j]: k=r*5+v (15 used), padded
  int bid = blockIdx.x;
  int b = bid >> 5, tile = bid & 31;
  int r0 = tile * 16;
  int t = threadIdx.x, w = t >> 6, l = t & 63;
  for (int idx = t; idx < 2560; idx += 256) {
    int j = idx / 5, v = idx % 5;
    belT[v][j]      = out[OFF_B1 + (size_t)b * 2560 + idx];
    belT[5 + v][j]  = out[OFF_B2 + (size_t)b * 2560 + idx];
    belT[10 + v][j] = out[OFF_B3 + (size_t)b * 2560 + idx];
  }
  __syncthreads();
  #pragma unroll 1
  for (int rr = 0; rr < 4; ++rr) {
    int row = r0 + w * 4 + rr;
    size_t base = ((size_t)b * 512 + row) * 512;
    float bi[15];
    #pragma unroll
    for (int k = 0; k < 15; ++k) bi[k] = belT[k][row];
    float a[8], s1[8], s2[8], s3[8];
    float p1 = 0.f, p2 = 0.f, p3 = 0.f;
    #pragma unroll
    for (int c = 0; c < 8; ++c) {
      int col = l + 64 * c;
      a[c] = A[base + col];
      float t1 = 0.f, t2 = 0.f, t3 = 0.f;
      #pragma unroll
      for (int v = 0; v < 5; ++v) {
        t1 += bi[v] * belT[v][col];
        t2 += bi[5 + v] * belT[5 + v][col];
        t3 += bi[10 + v] * belT[10 + v][col];
      }
      s1[c] = t1; s2[c] = t2; s3[c] = t3;
      p1 += a[c] * t1; p2 += a[c] * t2; p3 += a[c] * t3;
    }
    #pragma unroll
    for (int off = 1; off < 64; off <<= 1) {
      p1 += __shfl_xor(p1, off, 64);
      p2 += __shfl_xor(p2, off, 64);
      p3 += __shfl_xor(p3, off, 64);
    }
    float inv1 = 1.f / (p1 + EPSF), inv2 = 1.f / (p2 + EPSF), inv3 = 1.f / (p3 + EPSF);
    #pragma unroll
    for (int c = 0; c < 8; ++c) {
      int col = l + 64 * c;
      out[OFF_A   + base + col] = a[c];
      out[OFF_AF1 + base + col] = a[c] * s1[c] * inv1;
      out[OFF_AF2 + base + col] = a[c] * s2[c] * inv2;
      out[OFF_AF3 + base + col] = a[c] * s3[c] * inv3;
    }
  }
}

extern "C" void kernel_launch(void* const* d_in, const int* in_sizes, int n_in,
                              void* d_out, int out_size, void* d_ws, size_t ws_size,
                              hipStream_t stream) {
  (void)in_sizes; (void)n_in; (void)out_size; (void)d_ws; (void)ws_size;
  const float* inp  = (const float*)d_in[0];
  const float* aff  = (const float*)d_in[1];
  const float* una  = (const float*)d_in[2];
  const float* binc = (const float*)d_in[3];
  const int*   lab  = (const int*)d_in[4];
  const float* W1 = (const float*)d_in[6];
  const float* b1 = (const float*)d_in[7];
  const float* W2 = (const float*)d_in[8];
  const float* b2 = (const float*)d_in[9];
  float* out = (float*)d_out;

  k_rowsum<<<8192, 256, 0, stream>>>(aff, out + RS_OFF);
  k_mgemm<64, false><<<512, 256, 0, stream>>>(inp, 65536, W1, 0, out + Y1_OFF, nullptr, nullptr, 128);
  k_mgemm<64, true ><<<512, 256, 0, stream>>>(aff, 262144, out + Y1_OFF, 32768, out + X1_OFF, out + RS_OFF, b1, 512);
  k_bc<64><<<128, 256, 0, stream>>>(out + X1_OFF, lab, out + OFF_B3, 2500);
  k_mgemm<32, false><<<512, 256, 0, stream>>>(out + X1_OFF, 32768, W2, 0, out + Y2_OFF, nullptr, nullptr, 64);
  k_mgemm<32, true ><<<512, 256, 0, stream>>>(aff, 262144, out + Y2_OFF, 16384, out + X2_OFF, out + RS_OFF, b2, 512);
  k_bc<32><<<128, 256, 0, stream>>>(out + X2_OFF, lab, out + OFF_B3, 2525);
  k_At<<<4096, 256, 0, stream>>>(aff, out + AT_OFF);
  k_bp<<<128, 1024, 0, stream>>>(out + AT_OFF, una, binc, lab, out);
  k_aff<<<4096, 256, 0, stream>>>(aff, out);
}

// Round 5
// 591.911 us; speedup vs baseline: 1.8830x; 1.8830x over previous
//
#include <hip/hip_runtime.h>
#include <math.h>

#define EPSF 1e-6f
#define BP_ITERS 7

// ---- d_out layout (float offsets) ----
#define OFF_A    0ull
#define OFF_B1   33554432ull
#define OFF_B2   33882112ull
#define OFF_B3   34209792ull
#define OFF_AF1  34537472ull
#define OFF_AF2  68091904ull
#define OFF_AF3  101646336ull
// scratch parked inside d_out (regions dead until later kernels overwrite them)
#define Y1_OFF  (OFF_AF1)                 // [B][512][64] fp32
#define X1_OFF  (OFF_AF1 + 4194304ull)    // [B][512][64] fp32
#define Y2_OFF  (OFF_AF2)                 // [B][512][32] fp32
#define X2_OFF  (OFF_AF2 + 2097152ull)    // [B][512][32] fp32
#define AT_OFF  (OFF_AF2 + 4194304ull)    // At[b][j(512)][i(256)] = A[b][256+i][j], 16777216 floats
#define PARKB   (OFF_AF2 + 20971520ull)   // bc1/bc2 park: b*64 + {0,32}; overwritten only by k_aff
#define RS_OFF  (OFF_AF3)                 // [B*512] rowsum(A) fp32 (overwritten by k_aff at the end)

typedef __attribute__((ext_vector_type(8))) short bf16x8;
typedef __attribute__((ext_vector_type(4))) short s16x4;
typedef __attribute__((ext_vector_type(4))) float f32x4;

__device__ __forceinline__ short f2bf(float f) {
  unsigned u = __float_as_uint(f);
  unsigned r = (u + 0x7fffu + ((u >> 16) & 1u)) >> 16;
  return (short)r;
}
__device__ __forceinline__ float bf2f(short h) {
  return __uint_as_float(((unsigned)(unsigned short)h) << 16);
}

// ---------------- 1. row sums of A ----------------
__global__ __launch_bounds__(256) void k_rowsum(const float* __restrict__ A, float* __restrict__ rs) {
  int wid = threadIdx.x >> 6, lane = threadIdx.x & 63;
  for (int rr = 0; rr < 2; ++rr) {
    size_t row = (size_t)blockIdx.x * 8 + wid * 2 + rr; // = b*512+n
    const float4* src = (const float4*)(A + row * 512);
    float4 v0 = src[lane * 2], v1 = src[lane * 2 + 1];
    float s = v0.x + v0.y + v0.z + v0.w + v1.x + v1.y + v1.z + v1.w;
    #pragma unroll
    for (int off = 1; off < 64; off <<= 1) s += __shfl_xor(s, off, 64);
    if (lane == 0) rs[row] = s;
  }
}

// ---------------- 2. split-bf16 MFMA GEMM: C[b](512xBN) = A[b](512xK) @ B(KxBN) ----------------
template<int BN, bool POST>
__global__ __launch_bounds__(256) void k_mgemm(const float* __restrict__ Ain, size_t astride,
                                               const float* __restrict__ Bin, size_t bstride,
                                               float* __restrict__ Cout,
                                               const float* __restrict__ rowsum,
                                               const float* __restrict__ bias, int K) {
  constexpr int BM = 128, BK = 64, LDA = BK + 8;
  constexpr int NF = BN / 16;
  __shared__ short Ahi[BM * LDA], Alo[BM * LDA];
  __shared__ short Bhi[BN * LDA], Blo[BN * LDA];
  __shared__ float rs[BM];
  __shared__ float bls[BN];
  int b = blockIdx.x >> 2, mt = blockIdx.x & 3;
  int m0 = mt * BM;
  int t = threadIdx.x;
  int w = t >> 6, l = t & 63;
  if constexpr (POST) {
    if (t < BM) rs[t] = rowsum[(size_t)b * 512 + m0 + t];
    if (t < BN) bls[t] = bias[t];
  }
  const float* Ab = Ain + (size_t)b * astride + (size_t)m0 * K;
  const float* Bb = Bin + (size_t)b * bstride;
  f32x4 acc[2][NF];
  #pragma unroll
  for (int mf = 0; mf < 2; ++mf)
    #pragma unroll
    for (int nf = 0; nf < NF; ++nf) acc[mf][nf] = (f32x4){0.f, 0.f, 0.f, 0.f};

  for (int kt = 0; kt < K; kt += BK) {
    #pragma unroll
    for (int i = 0; i < 8; ++i) {
      int f = (t + i * 256) * 4;
      int r = f >> 6, k = f & 63;
      float4 v = *(const float4*)(Ab + (size_t)r * K + kt + k);
      float xs[4] = {v.x, v.y, v.z, v.w};
      s16x4 h, lo;
      #pragma unroll
      for (int e = 0; e < 4; ++e) {
        h[e] = f2bf(xs[e]);
        lo[e] = f2bf(xs[e] - bf2f(h[e]));
      }
      *(s16x4*)&Ahi[r * LDA + k] = h;
      *(s16x4*)&Alo[r * LDA + k] = lo;
    }
    #pragma unroll
    for (int i = 0; i < BK * BN / 1024; ++i) {
      int f = (t + i * 256) * 4;
      int k = f / BN, n = f % BN;
      float4 v = *(const float4*)(Bb + (size_t)(kt + k) * BN + n);
      float xs[4] = {v.x, v.y, v.z, v.w};
      #pragma unroll
      for (int e = 0; e < 4; ++e) {
        short h = f2bf(xs[e]);
        Bhi[(n + e) * LDA + k] = h;
        Blo[(n + e) * LDA + k] = f2bf(xs[e] - bf2f(h));
      }
    }
    __syncthreads();
    #pragma unroll
    for (int kc = 0; kc < 2; ++kc) {
      int kb = kc * 32 + (l >> 4) * 8;
      bf16x8 ah[2], al[2];
      #pragma unroll
      for (int mf = 0; mf < 2; ++mf) {
        int row = w * 32 + mf * 16 + (l & 15);
        ah[mf] = *(const bf16x8*)&Ahi[row * LDA + kb];
        al[mf] = *(const bf16x8*)&Alo[row * LDA + kb];
      }
      #pragma unroll
      for (int nf = 0; nf < NF; ++nf) {
        int col = nf * 16 + (l & 15);
        bf16x8 bh = *(const bf16x8*)&Bhi[col * LDA + kb];
        bf16x8 bl = *(const bf16x8*)&Blo[col * LDA + kb];
        #pragma unroll
        for (int mf = 0; mf < 2; ++mf) {
          acc[mf][nf] = __builtin_amdgcn_mfma_f32_16x16x32_bf16(ah[mf], bh, acc[mf][nf], 0, 0, 0);
          acc[mf][nf] = __builtin_amdgcn_mfma_f32_16x16x32_bf16(ah[mf], bl, acc[mf][nf], 0, 0, 0);
          acc[mf][nf] = __builtin_amdgcn_mfma_f32_16x16x32_bf16(al[mf], bh, acc[mf][nf], 0, 0, 0);
        }
      }
    }
    __syncthreads();
  }
  #pragma unroll
  for (int mf = 0; mf < 2; ++mf) {
    #pragma unroll
    for (int nf = 0; nf < NF; ++nf) {
      int col = nf * 16 + (l & 15);
      #pragma unroll
      for (int i = 0; i < 4; ++i) {
        int rloc = w * 32 + mf * 16 + (l >> 4) * 4 + i;
        float x = acc[mf][nf][i];
        if constexpr (POST) x = fmaxf(x / (rs[rloc] + EPSF) + bls[col], 0.f);
        Cout[((size_t)b * 512 + m0 + rloc) * BN + col] = x;
      }
    }
  }
}

// ---------------- 3. binary_comp_calc ----------------
template<int D>
__global__ __launch_bounds__(256) void k_bc(const float* __restrict__ X, const int* __restrict__ labels,
                                            float* __restrict__ dst, int parkoff) {
  constexpr int SL = 256 / D;
  constexpr int NPER = 512 / SL;
  __shared__ int labs[512];
  __shared__ float part[SL * 5 * D];
  __shared__ float cnt[5], nrm[5], proto[5 * D], dots[25];
  int b = blockIdx.x, t = threadIdx.x;
  labs[t] = labels[b * 512 + t];
  labs[t + 256] = labels[b * 512 + 256 + t];
  if (t < 5) { cnt[t] = 0.f; nrm[t] = 0.f; }
  __syncthreads();
  if (t < 128) {
    #pragma unroll
    for (int k = 0; k < 4; ++k) atomicAdd(&cnt[labs[t * 4 + k]], 1.f);
  }
  {
    int s = t / D, d = t % D;
    float a5[5] = {};
    for (int k = 0; k < NPER; ++k) {
      int n = s * NPER + k;
      float x = X[((size_t)b * 512 + n) * D + d];
      int lab = labs[n];
      #pragma unroll
      for (int w = 0; w < 5; ++w) a5[w] += (lab == w) ? x : 0.f;
    }
    #pragma unroll
    for (int w = 0; w < 5; ++w) part[(s * 5 + w) * D + d] = a5[w];
  }
  __syncthreads();
  for (int idx = t; idx < 5 * D; idx += 256) {
    int w = idx / D, dd = idx % D;
    float p = 0.f;
    #pragma unroll
    for (int s2 = 0; s2 < SL; ++s2) p += part[(s2 * 5 + w) * D + dd];
    p /= (cnt[w] + EPSF);
    proto[w * D + dd] = p;
    atomicAdd(&nrm[w], p * p);
  }
  __syncthreads();
  if (t < 25) {
    int w = t / 5, v = t % 5;
    float sdot = 0.f;
    for (int dd = 0; dd < D; ++dd) sdot += proto[w * D + dd] * proto[v * D + dd];
    dots[t] = sdot / ((sqrtf(nrm[w]) + EPSF) * (sqrtf(nrm[v]) + EPSF));
  }
  __syncthreads();
  if (t < 25) {
    int w = t / 5;
    float m = dots[w * 5];
    #pragma unroll
    for (int u = 1; u < 5; ++u) m = fmaxf(m, dots[w * 5 + u]);
    float ssum = 0.f;
    #pragma unroll
    for (int u = 0; u < 5; ++u) ssum += expf(dots[w * 5 + u] - m);
    dst[(size_t)b * 64 + parkoff + t] = expf(dots[t] - m) / ssum;
  }
}

// ---------------- 4. transpose rows 256..511 of A: At[b][j][i] = A[b][256+i][j] ----------------
__global__ __launch_bounds__(256) void k_At(const float* __restrict__ A, float* __restrict__ Atr) {
  __shared__ float T[64][65];
  int bid = blockIdx.x;
  int b = bid >> 5, r = bid & 31, jt = r >> 2, it = r & 3;
  int j0 = jt * 64, i0 = it * 64;
  int t = threadIdx.x;
  #pragma unroll
  for (int c = 0; c < 4; ++c) {
    int flat = (t + c * 256) * 4;
    int ii = flat >> 6, jj = flat & 63;
    float4 v = *(const float4*)(A + ((size_t)b * 512 + 256 + i0 + ii) * 512 + j0 + jj);
    T[ii][jj] = v.x; T[ii][jj + 1] = v.y; T[ii][jj + 2] = v.z; T[ii][jj + 3] = v.w;
  }
  __syncthreads();
  #pragma unroll
  for (int c = 0; c < 4; ++c) {
    int flat = (t + c * 256) * 4;
    int jj = flat >> 6, ii = flat & 63;
    float4 v = make_float4(T[ii][jj], T[ii + 1][jj], T[ii + 2][jj], T[ii + 3][jj]);
    *(float4*)(Atr + ((size_t)b * 512 + j0 + jj) * 256 + i0 + ii) = v;
  }
}

// ---------------- 5. per-round BP: grid = 3 rounds x 128 batches, A register-resident ----------------
__global__ __launch_bounds__(1024, 4) void k_bp(const float* __restrict__ Atr,
                                                const float* __restrict__ unary,
                                                const float* __restrict__ binc,
                                                const int* __restrict__ labels,
                                                float* __restrict__ out) {
  __shared__ float cbuf[256 * 8];   // c[j][0..4], stride 8 (b128-aligned)
  __shared__ float b3s[256 * 5];    // free-node beliefs
  __shared__ float msg[256 * 5];    // atomic combine; stride 5, gcd(5,32)=1 -> conflict-free
  __shared__ float binl[5 * 8];
  __shared__ int labs[256];
  int bid = blockIdx.x;
  int r = bid % 3, b = bid / 3;
  int t = threadIdx.x;
  int w = t >> 6, l = t & 63;
  int wh = w & 1, jc = w >> 1;      // i-half, j-chunk [32*jc, 32*jc+32)
  int i0 = wh * 128 + l;            // lane's i values: i0, i0+64
  if (t < 256) labs[t] = labels[b * 512 + t];
  if (t < 25) {
    float val;
    if (r == 0)      val = binc[b * 25 + t];
    else if (r == 1) val = out[PARKB + (size_t)b * 64 + t];
    else             val = out[PARKB + (size_t)b * 64 + 32 + t];
    binl[(t / 5) * 8 + (t % 5)] = val;
  }
  __syncthreads();
  // P1 (t<256): unary load (kept in regs), b0 = softmax(u), support-c into cbuf
  float u[5] = {};
  if (t < 256) {
    size_t ub = ((size_t)b * 512 + 256 + t) * 5;
    #pragma unroll
    for (int v = 0; v < 5; ++v) u[v] = unary[ub + v];
    float m = u[0];
    #pragma unroll
    for (int v = 1; v < 5; ++v) m = fmaxf(m, u[v]);
    float e[5], ssum = 0.f;
    #pragma unroll
    for (int v = 0; v < 5; ++v) { e[v] = expf(u[v] - m); ssum += e[v]; }
    float inv = 1.f / ssum;
    #pragma unroll
    for (int v = 0; v < 5; ++v) b3s[t * 5 + v] = e[v] * inv;
    int lab = labs[t];
    #pragma unroll
    for (int v = 0; v < 5; ++v) cbuf[t * 8 + v] = binl[lab * 8 + v];
  }
  __syncthreads();
  // P2: support partial (regs) + free-block A -> regs (held across all iterations)
  float asup[2][5] = {};
  float af[32][2];
  #pragma unroll
  for (int jj = 0; jj < 32; ++jj) {
    int j = jc * 32 + jj;
    float4 cq = *(const float4*)&cbuf[j * 8];
    float c4 = cbuf[j * 8 + 4];
    float ck[5] = {cq.x, cq.y, cq.z, cq.w, c4};
    size_t sbase = ((size_t)b * 512 + j) * 256 + i0;
    float a0 = Atr[sbase], a1 = Atr[sbase + 64];
    #pragma unroll
    for (int k = 0; k < 5; ++k) { asup[0][k] += a0 * ck[k]; asup[1][k] += a1 * ck[k]; }
    size_t fbase = ((size_t)b * 512 + 256 + j) * 256 + i0;
    af[jj][0] = Atr[fbase]; af[jj][1] = Atr[fbase + 64];
  }
  __syncthreads();
  for (int it = 0; it < BP_ITERS; ++it) {
    // A-phase (t<256): c[t] = b[t] @ binary ; zero msg (ALL 1280 entries: t<1024 + first 256 wrap)
    if (t < 256) {
      float bb[5];
      #pragma unroll
      for (int v = 0; v < 5; ++v) bb[v] = b3s[t * 5 + v];
      #pragma unroll
      for (int v = 0; v < 5; ++v) {
        float s = 0.f;
        #pragma unroll
        for (int ww = 0; ww < 5; ++ww) s += bb[ww] * binl[ww * 8 + v];
        cbuf[t * 8 + v] = s;
      }
    }
    if (t < 1280) msg[t] = 0.f;           // t<1024 always true -> msg[0..1023]
    if (t < 256) msg[t + 1024] = 0.f;     // msg[1024..1279]
    __syncthreads();
    // B-phase: 16 waves, register A
    {
      float acc[2][5];
      #pragma unroll
      for (int g = 0; g < 2; ++g)
        #pragma unroll
        for (int k = 0; k < 5; ++k) acc[g][k] = asup[g][k];
      #pragma unroll
      for (int jj = 0; jj < 32; ++jj) {
        int j = jc * 32 + jj;
        float4 cq = *(const float4*)&cbuf[j * 8];
        float c4 = cbuf[j * 8 + 4];
        float ck[5] = {cq.x, cq.y, cq.z, cq.w, c4};
        #pragma unroll
        for (int k = 0; k < 5; ++k) {
          acc[0][k] += af[jj][0] * ck[k];
          acc[1][k] += af[jj][1] * ck[k];
        }
      }
      #pragma unroll
      for (int g = 0; g < 2; ++g)
        #pragma unroll
        for (int k = 0; k < 5; ++k) atomicAdd(&msg[(i0 + 64 * g) * 5 + k], acc[g][k]);
    }
    __syncthreads();
    // C-phase (t<256): b = softmax(u + msg)
    if (t < 256) {
      float lg[5];
      #pragma unroll
      for (int v = 0; v < 5; ++v) lg[v] = u[v] + msg[t * 5 + v];
      float m = lg[0];
      #pragma unroll
      for (int v = 1; v < 5; ++v) m = fmaxf(m, lg[v]);
      float e[5], ssum = 0.f;
      #pragma unroll
      for (int v = 0; v < 5; ++v) { e[v] = expf(lg[v] - m); ssum += e[v]; }
      float inv = 1.f / ssum;
      #pragma unroll
      for (int v = 0; v < 5; ++v) b3s[t * 5 + v] = e[v] * inv;
    }
    __syncthreads();
  }
  // P4 (t<512): write this round's clamped beliefs
  if (t < 512) {
    int n = t;
    float bel[5];
    if (n < 256) {
      int lab = labs[n];
      #pragma unroll
      for (int v = 0; v < 5; ++v) bel[v] = (v == lab) ? 1.f : 0.f;
    } else {
      #pragma unroll
      for (int v = 0; v < 5; ++v) bel[v] = b3s[(n - 256) * 5 + v];
    }
    size_t base = OFF_B1 + (size_t)r * 327680ull + ((size_t)b * 512 + n) * 5;
    #pragma unroll
    for (int v = 0; v < 5; ++v) out[base + v] = bel[v];
  }
}

// ---------------- 6. fused affinity pass: A-copy + aff1 + aff2 + aff3 in one sweep ----------------
__global__ __launch_bounds__(256) void k_aff(const float* __restrict__ A, float* __restrict__ out) {
  __shared__ float belT[16][520];   // [k][j]: k=r*5+v (15 used), padded
  int bid = blockIdx.x;
  int b = bid >> 5, tile = bid & 31;
  int r0 = tile * 16;
  int t = threadIdx.x, w = t >> 6, l = t & 63;
  for (int idx = t; idx < 2560; idx += 256) {
    int j = idx / 5, v = idx % 5;
    belT[v][j]      = out[OFF_B1 + (size_t)b * 2560 + idx];
    belT[5 + v][j]  = out[OFF_B2 + (size_t)b * 2560 + idx];
    belT[10 + v][j] = out[OFF_B3 + (size_t)b * 2560 + idx];
  }
  __syncthreads();
  #pragma unroll 1
  for (int rr = 0; rr < 4; ++rr) {
    int row = r0 + w * 4 + rr;
    size_t base = ((size_t)b * 512 + row) * 512;
    float bi[15];
    #pragma unroll
    for (int k = 0; k < 15; ++k) bi[k] = belT[k][row];
    float a[8], s1[8], s2[8], s3[8];
    float p1 = 0.f, p2 = 0.f, p3 = 0.f;
    #pragma unroll
    for (int c = 0; c < 8; ++c) {
      int col = l + 64 * c;
      a[c] = A[base + col];
      float t1 = 0.f, t2 = 0.f, t3 = 0.f;
      #pragma unroll
      for (int v = 0; v < 5; ++v) {
        t1 += bi[v] * belT[v][col];
        t2 += bi[5 + v] * belT[5 + v][col];
        t3 += bi[10 + v] * belT[10 + v][col];
      }
      s1[c] = t1; s2[c] = t2; s3[c] = t3;
      p1 += a[c] * t1; p2 += a[c] * t2; p3 += a[c] * t3;
    }
    #pragma unroll
    for (int off = 1; off < 64; off <<= 1) {
      p1 += __shfl_xor(p1, off, 64);
      p2 += __shfl_xor(p2, off, 64);
      p3 += __shfl_xor(p3, off, 64);
    }
    float inv1 = 1.f / (p1 + EPSF), inv2 = 1.f / (p2 + EPSF), inv3 = 1.f / (p3 + EPSF);
    #pragma unroll
    for (int c = 0; c < 8; ++c) {
      int col = l + 64 * c;
      out[OFF_A   + base + col] = a[c];
      out[OFF_AF1 + base + col] = a[c] * s1[c] * inv1;
      out[OFF_AF2 + base + col] = a[c] * s2[c] * inv2;
      out[OFF_AF3 + base + col] = a[c] * s3[c] * inv3;
    }
  }
}

extern "C" void kernel_launch(void* const* d_in, const int* in_sizes, int n_in,
                              void* d_out, int out_size, void* d_ws, size_t ws_size,
                              hipStream_t stream) {
  (void)in_sizes; (void)n_in; (void)out_size; (void)d_ws; (void)ws_size;
  const float* inp  = (const float*)d_in[0];
  const float* aff  = (const float*)d_in[1];
  const float* una  = (const float*)d_in[2];
  const float* binc = (const float*)d_in[3];
  const int*   lab  = (const int*)d_in[4];
  const float* W1 = (const float*)d_in[6];
  const float* b1 = (const float*)d_in[7];
  const float* W2 = (const float*)d_in[8];
  const float* b2 = (const float*)d_in[9];
  float* out = (float*)d_out;

  k_rowsum<<<8192, 256, 0, stream>>>(aff, out + RS_OFF);
  k_mgemm<64, false><<<512, 256, 0, stream>>>(inp, 65536, W1, 0, out + Y1_OFF, nullptr, nullptr, 128);
  k_mgemm<64, true ><<<512, 256, 0, stream>>>(aff, 262144, out + Y1_OFF, 32768, out + X1_OFF, out + RS_OFF, b1, 512);
  k_bc<64><<<128, 256, 0, stream>>>(out + X1_OFF, lab, out + PARKB, 0);
  k_mgemm<32, false><<<512, 256, 0, stream>>>(out + X1_OFF, 32768, W2, 0, out + Y2_OFF, nullptr, nullptr, 64);
  k_mgemm<32, true ><<<512, 256, 0, stream>>>(aff, 262144, out + Y2_OFF, 16384, out + X2_OFF, out + RS_OFF, b2, 512);
  k_bc<32><<<128, 256, 0, stream>>>(out + X2_OFF, lab, out + PARKB, 32);
  k_At<<<4096, 256, 0, stream>>>(aff, out + AT_OFF);
  k_bp<<<384, 1024, 0, stream>>>(out + AT_OFF, una, binc, lab, out);
  k_aff<<<4096, 256, 0, stream>>>(aff, out);
}